// Round 13
// baseline (167.999 us; speedup 1.0000x reference)
//
#include <hip/hip_runtime.h>

#define SEQ    1024
#define BATCH  512
#define NTAGS  48
#define CPB    16   // chains per block (MFMA N)
#define CH     4    // steps per LDS-staged chunk
#define NCHUNK 128

typedef float f32x4 __attribute__((ext_vector_type(4)));
typedef short s16x8 __attribute__((ext_vector_type(8)));

__device__ __forceinline__ unsigned short f2bf(float x) {
  unsigned u = __float_as_uint(x);
  return (unsigned short)((u + 0x7fffu + ((u >> 16) & 1u)) >> 16);
}
__device__ __forceinline__ unsigned cvtpk(float lo, float hi) {
  unsigned r;
  asm("v_cvt_pk_bf16_f32 %0, %1, %2" : "=v"(r) : "v"(lo), "v"(hi));
  return r;
}
#define PL32(a, b) asm("v_permlane32_swap_b32 %0, %1" : "+v"(a), "+v"(b))
#define PL16(a, b) asm("v_permlane16_swap_b32 %0, %1" : "+v"(a), "+v"(b))

// global -> LDS direct copy, 16B per lane (dest = lds + lane*16)
__device__ __forceinline__ void gll16(const float* g, float* lds) {
  __builtin_amdgcn_global_load_lds(
      (const unsigned int __attribute__((address_space(1)))*)g,
      (unsigned int __attribute__((address_space(3)))*)lds, 16, 0, 0);
}

// One wave = 16 chains; MFMA + permlane step identical to r12 (verified).
// NEW: emissions staged via global_load_lds into 3 LDS buffers, 2 chunks
// ahead, counted vmcnt(12/16) -- un-sinkable by the compiler (r12's register
// staging was silently rematerialized to loads-at-use: VGPR=116 < needed,
// putting ~600cy HBM latency back on the serial path).
template <int DIR, int MASKED>
__device__ __forceinline__ void run_dir(
    const float* __restrict__ em, const int* __restrict__ mask,
    const float* __restrict__ start_t, const float* __restrict__ end_t,
    const float* __restrict__ trans,
    float* __restrict__ vout, float* __restrict__ cout, int b0,
    float* __restrict__ B0s, float* __restrict__ B1s, float* __restrict__ B2s)
{
  const int l = threadIdx.x, n = l & 15, q = l >> 4;
  const size_t strideT = (size_t)BATCH * NTAGS;
  const float* eb = em + (size_t)(b0 + n) * NTAGS + 4 * q;

  // Static A fragments (verified r10/r12)
  s16x8 A[3][2];
#pragma unroll
  for (int tau = 0; tau < 3; ++tau)
#pragma unroll
    for (int kap = 0; kap < 2; ++kap) {
      s16x8 tmp;
#pragma unroll
      for (int j = 0; j < 8; ++j) {
        int k = 8 * q + j + 32 * kap;
        float w = 0.f;
        if (k < NTAGS)
          w = __expf(DIR == 0 ? trans[k * NTAGS + 16 * tau + n]
                              : trans[(16 * tau + n) * NTAGS + k]);
        tmp[j] = (short)f2bf(w);
      }
      A[tau][kap] = tmp;
    }

  // init state
  f32x4 d[3];
#pragma unroll
  for (int tau = 0; tau < 3; ++tau) {
    if (DIR == 0) {
      f32x4 s4 = *(const f32x4*)(start_t + 16 * tau + 4 * q);
      f32x4 e4 = *(const f32x4*)(eb + 16 * tau);
#pragma unroll
      for (int r = 0; r < 4; ++r) d[tau][r] = __expf(s4[r] + e4[r]);
    } else {
      f32x4 e4 = *(const f32x4*)(end_t + 16 * tau + 4 * q);
#pragma unroll
      for (int r = 0; r < 4; ++r) d[tau][r] = __expf(e4[r]);
    }
  }

  float cX = 0.f;
  f32x4 Exc[3];
  int M0[CH], M1[CH], M2[CH];

#define TIDX(k, p) ((DIR == 0) ? (4 * (k) + (p)) : (1023 - 4 * (k) - (p)))

  // stage chunk kk (4 steps x 768 contiguous floats) into LDS buffer SB
#define STAGE(SB, kk) do {                                            \
    _Pragma("unroll")                                                 \
    for (int tt_ = 0; tt_ < CH; ++tt_) {                              \
      const float* tb_ = em + (size_t)TIDX(kk, tt_) * strideT         \
                            + (size_t)b0 * NTAGS;                     \
      gll16(tb_ +   0 + 4 * l, (SB) + tt_ * 768 +   0);               \
      gll16(tb_ + 256 + 4 * l, (SB) + tt_ * 768 + 256);               \
      gll16(tb_ + 512 + 4 * l, (SB) + tt_ * 768 + 512);               \
    }                                                                 \
  } while (0)

#define MSTAGE(MS, kk) do {                                           \
    if (MASKED) {                                                     \
      _Pragma("unroll")                                               \
      for (int p_ = 0; p_ < CH; ++p_)                                 \
        (MS)[p_] = mask[TIDX(kk, p_) * BATCH + b0 + n];               \
    }                                                                 \
  } while (0)

#define VEXP4(D, S) do {                                              \
    _Pragma("unroll")                                                 \
    for (int r_ = 0; r_ < 4; ++r_) (D)[r_] = __expf((S)[r_]);         \
  } while (0)

#define WAITLDS() do {                                                \
    if (MASKED) asm volatile("s_waitcnt vmcnt(16)" ::: "memory");     \
    else        asm volatile("s_waitcnt vmcnt(12)" ::: "memory");     \
  } while (0)

  // read next step's emissions from LDS buffer RB (tstep ts), build Exc
#define EXCNEXT(RB, ts) do {                                          \
    const float* rp_ = (RB) + (ts) * 768 + n * 48 + 4 * q;            \
    f32x4 R0_ = *(const f32x4*)(rp_);                                 \
    f32x4 R1_ = *(const f32x4*)(rp_ + 16);                            \
    f32x4 R2_ = *(const f32x4*)(rp_ + 32);                            \
    VEXP4(Exc[0], R0_); VEXP4(Exc[1], R1_); VEXP4(Exc[2], R2_);       \
  } while (0)

  // one step at compile-time chunk position p (verified r12 math path)
#define STEPM(p, CB, NB, MC) do {                                     \
    f32x4 v0, v1, v2;                                                 \
    if (DIR == 0) { v0 = d[0]; v1 = d[1]; v2 = d[2]; }                \
    else { v0 = d[0] * Exc[0]; v1 = d[1] * Exc[1]; v2 = d[2] * Exc[2]; } \
    float pv = 0.f;                                                   \
    if ((p) == 3) {                                                   \
      int t1 = __float_as_int(v0[0]), t2 = t1;                        \
      PL32(t1, t2);                                                   \
      int t3 = t1;                                                    \
      PL16(t1, t3);                                                   \
      pv = __int_as_float(t1);                                        \
    }                                                                 \
    int rx0 = (int)cvtpk(v0[0], v0[1]), rx1 = (int)cvtpk(v0[2], v0[3]); \
    int ry0 = (int)cvtpk(v1[0], v1[1]), ry1 = (int)cvtpk(v1[2], v1[3]); \
    int za0 = (int)cvtpk(v2[0], v2[1]), za1 = (int)cvtpk(v2[2], v2[3]); \
    int zb0 = za0, zb1 = za1;                                         \
    PL32(rx0, ry0); PL16(rx0, ry0);                                   \
    PL32(rx1, ry1); PL16(rx1, ry1);                                   \
    PL32(za0, zb0); PL16(za0, zb0);                                   \
    PL32(za1, zb1); PL16(za1, zb1);                                   \
    int4 B0i = {rx0, rx1, ry0, ry1};                                  \
    int4 B1i = {za0, za1, zb0, zb1};                                  \
    s16x8 Bf0 = __builtin_bit_cast(s16x8, B0i);                       \
    s16x8 Bf1 = __builtin_bit_cast(s16x8, B1i);                       \
    const f32x4 z4 = {0.f, 0.f, 0.f, 0.f};                            \
    f32x4 n0 = __builtin_amdgcn_mfma_f32_16x16x32_bf16(A[0][0], Bf0, z4, 0, 0, 0); \
    f32x4 n1 = __builtin_amdgcn_mfma_f32_16x16x32_bf16(A[1][0], Bf0, z4, 0, 0, 0); \
    f32x4 n2 = __builtin_amdgcn_mfma_f32_16x16x32_bf16(A[2][0], Bf0, z4, 0, 0, 0); \
    n0 = __builtin_amdgcn_mfma_f32_16x16x32_bf16(A[0][1], Bf1, n0, 0, 0, 0); \
    n1 = __builtin_amdgcn_mfma_f32_16x16x32_bf16(A[1][1], Bf1, n1, 0, 0, 0); \
    n2 = __builtin_amdgcn_mfma_f32_16x16x32_bf16(A[2][1], Bf1, n2, 0, 0, 0); \
    if (DIR == 0) { n0 *= Exc[0]; n1 *= Exc[1]; n2 *= Exc[2]; }       \
    const bool mk = (!MASKED) || ((MC) != 0);                         \
    if ((p) == 3) {                                                   \
      float rm = __builtin_amdgcn_rcpf(pv);                           \
      cX += __logf(pv);                                               \
      d[0] = (mk ? n0 : d[0]) * rm;                                   \
      d[1] = (mk ? n1 : d[1]) * rm;                                   \
      d[2] = (mk ? n2 : d[2]) * rm;                                   \
    } else {                                                          \
      d[0] = mk ? n0 : d[0];                                          \
      d[1] = mk ? n1 : d[1];                                          \
      d[2] = mk ? n2 : d[2];                                          \
    }                                                                 \
    /* read-ahead: next step's emissions -> Exc */                    \
    if ((p) < 3) { EXCNEXT(CB, (p) + 1); }                            \
    else         { WAITLDS(); EXCNEXT(NB, 0); }                       \
  } while (0)

  // chunk k: stage k+2 into SB, run steps PSTART..3 on CB (read-ahead -> NB)
#define CHUNKX(CB, NB, SB, MC, MN, MS, k, PSTART) do {                \
    STAGE(SB, (k) + 2);                                               \
    MSTAGE(MS, (k) + 2);                                              \
    _Pragma("unroll")                                                 \
    for (int p_ = (PSTART); p_ < CH; ++p_)                            \
      STEPM(p_, CB, NB, (MASKED ? (MC)[p_] : 1));                     \
  } while (0)

  // prologue: stage chunks 0,1; one-time full drain; initial Exc
  STAGE(B0s, 0); MSTAGE(M0, 0);
  STAGE(B1s, 1); MSTAGE(M1, 1);
  asm volatile("s_waitcnt vmcnt(0)" ::: "memory");
  EXCNEXT(B0s, (DIR == 0) ? 1 : 0);

  CHUNKX(B0s, B1s, B2s, M0, M1, M2, 0, (DIR == 0) ? 1 : 0);
  for (int k = 1; k <= 124; k += 3) {
    CHUNKX(B1s, B2s, B0s, M1, M2, M0, k,     0);
    CHUNKX(B2s, B0s, B1s, M2, M0, M1, k + 1, 0);
    CHUNKX(B0s, B1s, B2s, M0, M1, M2, k + 2, 0);
  }
  CHUNKX(B1s, B2s, B0s, M1, M2, M0, 127, 0);

#pragma unroll
  for (int tau = 0; tau < 3; ++tau)
    *(f32x4*)(vout + (size_t)(b0 + n) * NTAGS + 16 * tau + 4 * q) = d[tau];
  if (l < 16) cout[b0 + l] = cX;
}

__global__ __launch_bounds__(64, 1) void crf_mfma_kernel(
    const float* __restrict__ em, const int* __restrict__ tags,
    const int* __restrict__ mask, const float* __restrict__ start_t,
    const float* __restrict__ end_t, const float* __restrict__ trans,
    float* __restrict__ alpha, float* __restrict__ beta,
    float* __restrict__ cfb, float* __restrict__ cbb,
    float* __restrict__ numb)
{
  __shared__ __align__(16) float slds[3][CH * 768];   // 36 KB
  const int bid = blockIdx.x;
  const int l = threadIdx.x;
  const size_t strideT = (size_t)BATCH * NTAGS;

  if (bid >= 64) {
    // -------- numerator for chain b (one wave per chain) --------
    const int b = bid - 64;
    float np = 0.f; int mcount = 0;
    for (int t = l; t < SEQ; t += 64) {
      int tag_t = tags[(size_t)t * BATCH + b];
      tag_t = min(max(tag_t, 0), NTAGS - 1);
      int mk = mask[t * BATCH + b];
      float e = em[(size_t)t * strideT + (size_t)b * NTAGS + tag_t];
      if (t == 0) np += start_t[tag_t] + e;
      else {
        int tag_p = tags[(size_t)(t - 1) * BATCH + b];
        tag_p = min(max(tag_p, 0), NTAGS - 1);
        np += (trans[tag_p * NTAGS + tag_t] + e) * (float)mk;
      }
      mcount += (mk != 0) ? 1 : 0;
    }
#pragma unroll
    for (int off = 32; off > 0; off >>= 1) {
      np += __shfl_xor(np, off);
      mcount += __shfl_xor(mcount, off);
    }
    int last_idx = min(max(mcount - 1, 0), SEQ - 1);
    int tag_last = tags[(size_t)last_idx * BATCH + b];
    tag_last = min(max(tag_last, 0), NTAGS - 1);
    if (l == 0) numb[b] = np + end_t[tag_last];
    return;
  }

  const int dir = bid >> 5;           // 0: fwd (blocks 0..31), 1: bwd (32..63)
  const int b0 = (bid & 31) * CPB;

  // all-ones mask check for this 16-chain group
  int myall = 1;
  for (int i = l; i < SEQ * CPB / 4; i += 64) {
    int fi = i << 2;
    int t = fi >> 4, c = fi & 15;
    int4 v = *(const int4*)&mask[t * BATCH + b0 + c];
    myall &= (v.x != 0) & (v.y != 0) & (v.z != 0) & (v.w != 0);
  }
  const bool allones = (__ballot(myall != 0) == ~0ull);

  if (dir == 0) {
    if (allones) run_dir<0, 0>(em, mask, start_t, end_t, trans, alpha, cfb, b0,
                               slds[0], slds[1], slds[2]);
    else         run_dir<0, 1>(em, mask, start_t, end_t, trans, alpha, cfb, b0,
                               slds[0], slds[1], slds[2]);
  } else {
    if (allones) run_dir<1, 0>(em, mask, start_t, end_t, trans, beta, cbb, b0,
                               slds[0], slds[1], slds[2]);
    else         run_dir<1, 1>(em, mask, start_t, end_t, trans, beta, cbb, b0,
                               slds[0], slds[1], slds[2]);
  }
}

// den = cf + cb + log(alpha_511 . beta_512); out = mean(num - den)
__global__ __launch_bounds__(512) void crf_combine_kernel(
    const float* __restrict__ alpha, const float* __restrict__ beta,
    const float* __restrict__ cfb,   const float* __restrict__ cbb,
    const float* __restrict__ numb,  float* __restrict__ out)
{
  const int tid = threadIdx.x;       // 0..511 = chain
  float dot = 0.0f;
#pragma unroll
  for (int j = 0; j < NTAGS; j += 4) {
    float4 av = *(const float4*)&alpha[tid * NTAGS + j];
    float4 bv = *(const float4*)&beta [tid * NTAGS + j];
    dot += av.x * bv.x + av.y * bv.y + av.z * bv.z + av.w * bv.w;
  }
  float den = cfb[tid] + cbb[tid] + __logf(dot);
  float v   = numb[tid] - den;
#pragma unroll
  for (int off = 32; off > 0; off >>= 1)
    v += __shfl_xor(v, off);
  __shared__ float sw[8];
  if ((tid & 63) == 0) sw[tid >> 6] = v;
  __syncthreads();
  if (tid == 0) {
    float s = 0.0f;
#pragma unroll
    for (int w = 0; w < 8; ++w) s += sw[w];
    out[0] = s * (1.0f / (float)BATCH);
  }
}

extern "C" void kernel_launch(void* const* d_in, const int* in_sizes, int n_in,
                              void* d_out, int out_size, void* d_ws, size_t ws_size,
                              hipStream_t stream) {
  const float* em   = (const float*)d_in[0];
  const int*   tg   = (const int*)  d_in[1];
  const int*   mask = (const int*)  d_in[2];
  const float* st   = (const float*)d_in[3];
  const float* en   = (const float*)d_in[4];
  const float* tr   = (const float*)d_in[5];

  float* ws    = (float*)d_ws;
  float* alpha = ws;                              // 512*48
  float* beta  = ws + BATCH * NTAGS;              // 512*48
  float* cfb   = ws + 2 * BATCH * NTAGS;          // 512
  float* cbb   = cfb + BATCH;                     // 512
  float* numb  = cbb + BATCH;                     // 512

  crf_mfma_kernel<<<64 + BATCH, 64, 0, stream>>>(em, tg, mask, st, en, tr,
                                                 alpha, beta, cfb, cbb, numb);
  crf_combine_kernel<<<1, 512, 0, stream>>>(alpha, beta, cfb, cbb, numb,
                                            (float*)d_out);
}

// Round 15
// 136.318 us; speedup vs baseline: 1.2324x; 1.2324x over previous
//
#include <hip/hip_runtime.h>

#define SEQ    1024
#define BATCH  512
#define NTAGS  48
#define CPB    16   // chains per block (MFMA N)

typedef float f32x4 __attribute__((ext_vector_type(4)));
typedef short s16x8 __attribute__((ext_vector_type(8)));

__device__ __forceinline__ unsigned short f2bf(float x) {
  unsigned u = __float_as_uint(x);
  return (unsigned short)((u + 0x7fffu + ((u >> 16) & 1u)) >> 16);
}
__device__ __forceinline__ unsigned cvtpk(float lo, float hi) {
  unsigned r;
  asm("v_cvt_pk_bf16_f32 %0, %1, %2" : "=v"(r) : "v"(lo), "v"(hi));
  return r;
}
#define PL32(a, b) asm("v_permlane32_swap_b32 %0, %1" : "+v"(a), "+v"(b))
#define PL16(a, b) asm("v_permlane16_swap_b32 %0, %1" : "+v"(a), "+v"(b))

// One wave = 16 chains; MFMA + permlane step math identical to r12 (verified
// absmax 0). FIX vs r12: (1) __launch_bounds__(64,1) lifts the VGPR cap to
// 256 -- r12's default bounds capped at ~128, forcing the compiler to demote
// the register staging buffers and rematerialize emission loads AT USE
// (VGPR=116 observed < ~170 required), putting ~500cy HBM latency on the
// serial chain; (2) three rotating 4-step chunk buffers staged 2 chunks
// ahead (~7-step slack); (3) sched_barrier(0) after each staging block pins
// the load issue early (loads cannot sink back toward their uses).
template <int DIR, int MASKED>
__device__ __forceinline__ void run_dir(
    const float* __restrict__ em, const int* __restrict__ mask,
    const float* __restrict__ start_t, const float* __restrict__ end_t,
    const float* __restrict__ trans,
    float* __restrict__ vout, float* __restrict__ cout, int b0)
{
  const int l = threadIdx.x, n = l & 15, q = l >> 4;
  const size_t strideT = (size_t)BATCH * NTAGS;
  const float* eb = em + (size_t)(b0 + n) * NTAGS + 4 * q;

  // Static A fragments: DIR==0 -> W^T; DIR==1 -> W. (verified r10/r12)
  s16x8 A[3][2];
#pragma unroll
  for (int tau = 0; tau < 3; ++tau)
#pragma unroll
    for (int kap = 0; kap < 2; ++kap) {
      s16x8 tmp;
#pragma unroll
      for (int j = 0; j < 8; ++j) {
        int k = 8 * q + j + 32 * kap;
        float w = 0.f;
        if (k < NTAGS)
          w = __expf(DIR == 0 ? trans[k * NTAGS + 16 * tau + n]
                              : trans[(16 * tau + n) * NTAGS + k]);
        tmp[j] = (short)f2bf(w);
      }
      A[tau][kap] = tmp;
    }

  // init state
  f32x4 d[3];
#pragma unroll
  for (int tau = 0; tau < 3; ++tau) {
    if (DIR == 0) {
      f32x4 s4 = *(const f32x4*)(start_t + 16 * tau + 4 * q);
      f32x4 e4 = *(const f32x4*)(eb + 16 * tau);
#pragma unroll
      for (int r = 0; r < 4; ++r) d[tau][r] = __expf(s4[r] + e4[r]);
    } else {
      f32x4 e4 = *(const f32x4*)(end_t + 16 * tau + 4 * q);
#pragma unroll
      for (int r = 0; r < 4; ++r) d[tau][r] = __expf(e4[r]);
    }
  }

  float cX = 0.f;
  f32x4 Exc[3];

  // step time: fwd t = 4k+p (chunk0 runs p=1..3); bwd u = 1023-4k-p
#define TIDX(k, p) ((DIR == 0) ? (4 * (k) + (p)) : (1023 - 4 * (k) - (p)))

  f32x4 EA[12], EB[12], EC[12];   // [p*3 + tau], 3 rotating chunk buffers
  int   M0[4], M1[4], M2[4];

#define LOADE(BUF, MBUF, kk) do {                                     \
    _Pragma("unroll")                                                 \
    for (int p_ = 0; p_ < 4; ++p_) {                                  \
      const float* pp_ = eb + (size_t)TIDX(kk, p_) * strideT;         \
      (BUF)[p_ * 3 + 0] = *(const f32x4*)(pp_);                       \
      (BUF)[p_ * 3 + 1] = *(const f32x4*)(pp_ + 16);                  \
      (BUF)[p_ * 3 + 2] = *(const f32x4*)(pp_ + 32);                  \
      if (MASKED) (MBUF)[p_] = mask[TIDX(kk, p_) * BATCH + b0 + n];   \
    }                                                                 \
    __builtin_amdgcn_sched_barrier(0);  /* pin load issue here */     \
  } while (0)

#define VEXP4(D, S) do {                                              \
    _Pragma("unroll")                                                 \
    for (int r_ = 0; r_ < 4; ++r_) (D)[r_] = __expf((S)[r_]);         \
  } while (0)

  // one step at compile-time chunk position p (r12 math path, verified)
#define STEPM(p, CUR, NXT, MC) do {                                   \
    f32x4 v0, v1, v2;                                                 \
    if (DIR == 0) { v0 = d[0]; v1 = d[1]; v2 = d[2]; }                \
    else { v0 = d[0] * Exc[0]; v1 = d[1] * Exc[1]; v2 = d[2] * Exc[2]; } \
    float pv = 0.f;                                                   \
    if ((p) == 3) {                                                   \
      int t1 = __float_as_int(v0[0]), t2 = t1;                        \
      PL32(t1, t2);                                                   \
      int t3 = t1;                                                    \
      PL16(t1, t3);                                                   \
      pv = __int_as_float(t1);                                        \
    }                                                                 \
    int rx0 = (int)cvtpk(v0[0], v0[1]), rx1 = (int)cvtpk(v0[2], v0[3]); \
    int ry0 = (int)cvtpk(v1[0], v1[1]), ry1 = (int)cvtpk(v1[2], v1[3]); \
    int za0 = (int)cvtpk(v2[0], v2[1]), za1 = (int)cvtpk(v2[2], v2[3]); \
    int zb0 = za0, zb1 = za1;                                         \
    PL32(rx0, ry0); PL16(rx0, ry0);                                   \
    PL32(rx1, ry1); PL16(rx1, ry1);                                   \
    PL32(za0, zb0); PL16(za0, zb0);                                   \
    PL32(za1, zb1); PL16(za1, zb1);                                   \
    int4 B0i = {rx0, rx1, ry0, ry1};                                  \
    int4 B1i = {za0, za1, zb0, zb1};                                  \
    s16x8 Bf0 = __builtin_bit_cast(s16x8, B0i);                       \
    s16x8 Bf1 = __builtin_bit_cast(s16x8, B1i);                       \
    const f32x4 z4 = {0.f, 0.f, 0.f, 0.f};                            \
    f32x4 n0 = __builtin_amdgcn_mfma_f32_16x16x32_bf16(A[0][0], Bf0, z4, 0, 0, 0); \
    f32x4 n1 = __builtin_amdgcn_mfma_f32_16x16x32_bf16(A[1][0], Bf0, z4, 0, 0, 0); \
    f32x4 n2 = __builtin_amdgcn_mfma_f32_16x16x32_bf16(A[2][0], Bf0, z4, 0, 0, 0); \
    n0 = __builtin_amdgcn_mfma_f32_16x16x32_bf16(A[0][1], Bf1, n0, 0, 0, 0); \
    n1 = __builtin_amdgcn_mfma_f32_16x16x32_bf16(A[1][1], Bf1, n1, 0, 0, 0); \
    n2 = __builtin_amdgcn_mfma_f32_16x16x32_bf16(A[2][1], Bf1, n2, 0, 0, 0); \
    if (DIR == 0) { n0 *= Exc[0]; n1 *= Exc[1]; n2 *= Exc[2]; }       \
    const bool mk = (!MASKED) || ((MC) != 0);                         \
    if ((p) == 3) {                                                   \
      float rm = __builtin_amdgcn_rcpf(pv);                           \
      cX += __logf(pv);                                               \
      d[0] = (mk ? n0 : d[0]) * rm;                                   \
      d[1] = (mk ? n1 : d[1]) * rm;                                   \
      d[2] = (mk ? n2 : d[2]) * rm;                                   \
    } else {                                                          \
      d[0] = mk ? n0 : d[0];                                          \
      d[1] = mk ? n1 : d[1];                                          \
      d[2] = mk ? n2 : d[2];                                          \
    }                                                                 \
    /* next step's Exc from resident chunk registers */               \
    if ((p) < 3) {                                                    \
      VEXP4(Exc[0], (CUR)[((p) + 1) * 3 + 0]);                        \
      VEXP4(Exc[1], (CUR)[((p) + 1) * 3 + 1]);                        \
      VEXP4(Exc[2], (CUR)[((p) + 1) * 3 + 2]);                        \
    } else {                                                          \
      VEXP4(Exc[0], (NXT)[0]);                                        \
      VEXP4(Exc[1], (NXT)[1]);                                        \
      VEXP4(Exc[2], (NXT)[2]);                                        \
    }                                                                 \
  } while (0)

  // chunk k: stage chunk k+2 into LD; run steps PSTART..3 on CUR
#define CHUNKM(CUR, MCUR, NXT, LD, MLD, k, PSTART) do {               \
    LOADE(LD, MLD, (k) + 2);                                          \
    _Pragma("unroll")                                                 \
    for (int p_ = (PSTART); p_ < 4; ++p_)                             \
      STEPM(p_, CUR, NXT, (MASKED ? (MCUR)[p_] : 1));                 \
  } while (0)

  LOADE(EA, M0, 0);
  LOADE(EB, M1, 1);
  {
    const int pst = (DIR == 0) ? 1 : 0;
    VEXP4(Exc[0], EA[pst * 3 + 0]);
    VEXP4(Exc[1], EA[pst * 3 + 1]);
    VEXP4(Exc[2], EA[pst * 3 + 2]);
  }

  CHUNKM(EA, M0, EB, EC, M2, 0, (DIR == 0) ? 1 : 0);
  for (int k = 1; k <= 124; k += 3) {
    CHUNKM(EB, M1, EC, EA, M0, k,     0);
    CHUNKM(EC, M2, EA, EB, M1, k + 1, 0);
    CHUNKM(EA, M0, EB, EC, M2, k + 2, 0);
  }
  CHUNKM(EB, M1, EC, EA, M0, 127, 0);

#pragma unroll
  for (int tau = 0; tau < 3; ++tau)
    *(f32x4*)(vout + (size_t)(b0 + n) * NTAGS + 16 * tau + 4 * q) = d[tau];
  if (l < 16) cout[b0 + l] = cX;
}

__global__ __launch_bounds__(64, 1) void crf_mfma_kernel(
    const float* __restrict__ em, const int* __restrict__ tags,
    const int* __restrict__ mask, const float* __restrict__ start_t,
    const float* __restrict__ end_t, const float* __restrict__ trans,
    float* __restrict__ alpha, float* __restrict__ beta,
    float* __restrict__ cfb, float* __restrict__ cbb,
    float* __restrict__ numb)
{
  const int bid = blockIdx.x;
  const int l = threadIdx.x;
  const size_t strideT = (size_t)BATCH * NTAGS;

  if (bid >= 64) {
    // -------- numerator for chain b (one wave per chain) --------
    const int b = bid - 64;
    float np = 0.f; int mcount = 0;
    for (int t = l; t < SEQ; t += 64) {
      int tag_t = tags[(size_t)t * BATCH + b];
      tag_t = min(max(tag_t, 0), NTAGS - 1);
      int mk = mask[t * BATCH + b];
      float e = em[(size_t)t * strideT + (size_t)b * NTAGS + tag_t];
      if (t == 0) np += start_t[tag_t] + e;
      else {
        int tag_p = tags[(size_t)(t - 1) * BATCH + b];
        tag_p = min(max(tag_p, 0), NTAGS - 1);
        np += (trans[tag_p * NTAGS + tag_t] + e) * (float)mk;
      }
      mcount += (mk != 0) ? 1 : 0;
    }
#pragma unroll
    for (int off = 32; off > 0; off >>= 1) {
      np += __shfl_xor(np, off);
      mcount += __shfl_xor(mcount, off);
    }
    int last_idx = min(max(mcount - 1, 0), SEQ - 1);
    int tag_last = tags[(size_t)last_idx * BATCH + b];
    tag_last = min(max(tag_last, 0), NTAGS - 1);
    if (l == 0) numb[b] = np + end_t[tag_last];
    return;
  }

  const int dir = bid >> 5;           // 0: fwd (blocks 0..31), 1: bwd (32..63)
  const int b0 = (bid & 31) * CPB;

  // all-ones mask check for this 16-chain group
  int myall = 1;
  for (int i = l; i < SEQ * CPB / 4; i += 64) {
    int fi = i << 2;
    int t = fi >> 4, c = fi & 15;
    int4 v = *(const int4*)&mask[t * BATCH + b0 + c];
    myall &= (v.x != 0) & (v.y != 0) & (v.z != 0) & (v.w != 0);
  }
  const bool allones = (__ballot(myall != 0) == ~0ull);

  if (dir == 0) {
    if (allones) run_dir<0, 0>(em, mask, start_t, end_t, trans, alpha, cfb, b0);
    else         run_dir<0, 1>(em, mask, start_t, end_t, trans, alpha, cfb, b0);
  } else {
    if (allones) run_dir<1, 0>(em, mask, start_t, end_t, trans, beta, cbb, b0);
    else         run_dir<1, 1>(em, mask, start_t, end_t, trans, beta, cbb, b0);
  }
}

// den = cf + cb + log(alpha_511 . beta_512); out = mean(num - den)
__global__ __launch_bounds__(512) void crf_combine_kernel(
    const float* __restrict__ alpha, const float* __restrict__ beta,
    const float* __restrict__ cfb,   const float* __restrict__ cbb,
    const float* __restrict__ numb,  float* __restrict__ out)
{
  const int tid = threadIdx.x;       // 0..511 = chain
  float dot = 0.0f;
#pragma unroll
  for (int j = 0; j < NTAGS; j += 4) {
    float4 av = *(const float4*)&alpha[tid * NTAGS + j];
    float4 bv = *(const float4*)&beta [tid * NTAGS + j];
    dot += av.x * bv.x + av.y * bv.y + av.z * bv.z + av.w * bv.w;
  }
  float den = cfb[tid] + cbb[tid] + __logf(dot);
  float v   = numb[tid] - den;
#pragma unroll
  for (int off = 32; off > 0; off >>= 1)
    v += __shfl_xor(v, off);
  __shared__ float sw[8];
  if ((tid & 63) == 0) sw[tid >> 6] = v;
  __syncthreads();
  if (tid == 0) {
    float s = 0.0f;
#pragma unroll
    for (int w = 0; w < 8; ++w) s += sw[w];
    out[0] = s * (1.0f / (float)BATCH);
  }
}

extern "C" void kernel_launch(void* const* d_in, const int* in_sizes, int n_in,
                              void* d_out, int out_size, void* d_ws, size_t ws_size,
                              hipStream_t stream) {
  const float* em   = (const float*)d_in[0];
  const int*   tg   = (const int*)  d_in[1];
  const int*   mask = (const int*)  d_in[2];
  const float* st   = (const float*)d_in[3];
  const float* en   = (const float*)d_in[4];
  const float* tr   = (const float*)d_in[5];

  float* ws    = (float*)d_ws;
  float* alpha = ws;                              // 512*48
  float* beta  = ws + BATCH * NTAGS;              // 512*48
  float* cfb   = ws + 2 * BATCH * NTAGS;          // 512
  float* cbb   = cfb + BATCH;                     // 512
  float* numb  = cbb + BATCH;                     // 512

  crf_mfma_kernel<<<64 + BATCH, 64, 0, stream>>>(em, tg, mask, st, en, tr,
                                                 alpha, beta, cfb, cbb, numb);
  crf_combine_kernel<<<1, 512, 0, stream>>>(alpha, beta, cfb, cbb, numb,
                                            (float*)d_out);
}